// Round 6
// baseline (406.652 us; speedup 1.0000x reference)
//
#include <hip/hip_runtime.h>
#include <math.h>

#define CCH 256
#define NPIX 4096
#define NB 4
#define NTOT (NB * NPIX)   // 16384 flat rows (b*4096 + n)

typedef _Float16 f16;
typedef f16 f16x8 __attribute__((ext_vector_type(8)));
typedef __fp16 fp16x2 __attribute__((ext_vector_type(2)));
typedef float f32x4 __attribute__((ext_vector_type(4)));
typedef unsigned short u16;
typedef unsigned int u32;

__device__ __forceinline__ u16 f2h(float f) {
  union { f16 h; u16 u; } c; c.h = (f16)f; return c.u;
}
__device__ __forceinline__ void fsplit(float v, u16& h, u16& l) {
  union { f16 h; u16 u; } a, b;
  a.h = (f16)v;                    // RN
  b.h = (f16)(v - (float)a.h);     // residual
  h = a.u; l = b.u;
}
__device__ __forceinline__ u32 pkh(float a, float b) {
  union { fp16x2 v; u32 u; } c;
  c.v = __builtin_amdgcn_cvt_pkrtz(a, b);
  return c.u;
}
__device__ __forceinline__ u32 shflu(u32 v, int s) { return (u32)__shfl((int)v, s, 64); }
__device__ __forceinline__ f32x4 mm(f16x8 a, f16x8 b, f32x4 c) {
  return __builtin_amdgcn_mfma_f32_16x16x32_f16(a, b, c, 0, 0, 0);
}
__device__ __forceinline__ f16x8 ld8(const u16* p) {
  return *reinterpret_cast<const f16x8*>(p);
}

using gas_t = const __attribute__((address_space(1))) void*;
using las_t = __attribute__((address_space(3))) void*;
__device__ __forceinline__ void gl2lds16(const void* g, void* l) {
  __builtin_amdgcn_global_load_lds((gas_t)g, (las_t)l, 16, 0, 0);
}

#define SB()  __builtin_amdgcn_sched_barrier(0)
#define BARN() __builtin_amdgcn_s_barrier()
#define ASMW(s) asm volatile("s_waitcnt " s ::: "memory")

// ---------------------------------------------------------------------------
// mm_wqwk: M = Wq^T * Wk  (fp32, 256x256, K=256). grid (4,4), block 256.
// ---------------------------------------------------------------------------
__global__ __launch_bounds__(256) void mm_wqwk(
    const float* __restrict__ Wq, const float* __restrict__ Wk,
    float* __restrict__ M)
{
  __shared__ float Aq[32][68], Ak[32][68];
  const int c1b = blockIdx.x * 64, c2b = blockIdx.y * 64;
  const int t = threadIdx.x, ty = t >> 4, tx = t & 15;
  float acc[4][4] = {};
  for (int os = 0; os < 256; os += 32) {
    __syncthreads();
    #pragma unroll
    for (int k = 0; k < 2; ++k) {
      int e = t + 256 * k, row = e >> 4, c4 = e & 15;
      *reinterpret_cast<float4*>(&Aq[row][c4 * 4]) =
          *reinterpret_cast<const float4*>(&Wq[(size_t)(os + row) * 256 + c1b + c4 * 4]);
      *reinterpret_cast<float4*>(&Ak[row][c4 * 4]) =
          *reinterpret_cast<const float4*>(&Wk[(size_t)(os + row) * 256 + c2b + c4 * 4]);
    }
    __syncthreads();
    #pragma unroll
    for (int o = 0; o < 32; ++o) {
      float4 a = *reinterpret_cast<const float4*>(&Aq[o][ty * 4]);
      float4 b = *reinterpret_cast<const float4*>(&Ak[o][tx * 4]);
      const float av[4] = {a.x, a.y, a.z, a.w};
      const float bv[4] = {b.x, b.y, b.z, b.w};
      #pragma unroll
      for (int i = 0; i < 4; ++i)
        #pragma unroll
        for (int j = 0; j < 4; ++j)
          acc[i][j] = fmaf(av[i], bv[j], acc[i][j]);
    }
  }
  #pragma unroll
  for (int i = 0; i < 4; ++i) {
    float4 r; r.x = acc[i][0]; r.y = acc[i][1]; r.z = acc[i][2]; r.w = acc[i][3];
    *reinterpret_cast<float4*>(&M[(size_t)(c1b + ty * 4 + i) * 256 + c2b + tx * 4]) = r;
  }
}

// ---------------------------------------------------------------------------
// gvec: g[c] = sum_o Wk[o][c] * bq[o].  1 block, 256 thr.
// ---------------------------------------------------------------------------
__global__ __launch_bounds__(256) void gvec(
    const float* __restrict__ Wk, const float* __restrict__ bq,
    float* __restrict__ g)
{
  const int c = threadIdx.x;
  float s = 0.f;
  for (int o = 0; o < 256; ++o) s = fmaf(Wk[(size_t)o * 256 + c], bq[o], s);
  g[c] = s;
}

// ---------------------------------------------------------------------------
// prep_w: split 4 fp32 [256][256] matrices {M, Wv, W1, W2} into fp16 h/l.
// ---------------------------------------------------------------------------
__global__ __launch_bounds__(256) void prep_w(
    const float* w0, const float* w1, const float* w2, const float* w3,
    u16* wp)
{
  const float* srcs[4] = {w0, w1, w2, w3};
  const int m = blockIdx.y;
  const float* s = srcs[m];
  u16* ph = wp + (size_t)m * 2 * 65536;
  u16* pl = ph + 65536;
  const int i = (blockIdx.x * 256 + threadIdx.x) * 4;
  float4 v = *reinterpret_cast<const float4*>(s + i);
  ushort4 hv, lv;
  fsplit(v.x, hv.x, lv.x); fsplit(v.y, hv.y, lv.y);
  fsplit(v.z, hv.z, lv.z); fsplit(v.w, hv.w, lv.w);
  *reinterpret_cast<ushort4*>(ph + i) = hv;
  *reinterpret_cast<ushort4*>(pl + i) = lv;
}

// ---------------------------------------------------------------------------
// transpose_split: x [b][c][n] f32 -> xT [b*n][c] fp16 hi/lo planes.
// ---------------------------------------------------------------------------
__global__ __launch_bounds__(256) void transpose_split(
    const float* xq, const float* xkv,
    u16* xqTh, u16* xqTl, u16* xkvTh, u16* xkvTl)
{
  __shared__ float T[64][65];
  const int nb = blockIdx.x * 64, cb = blockIdx.y * 64;
  const int z = blockIdx.z, b = z & 3, inp = z >> 2;
  const float* src = (inp ? xkv : xq) + (size_t)b * CCH * NPIX;
  u16* dh = inp ? xkvTh : xqTh;
  u16* dl = inp ? xkvTl : xqTl;
  const int t = threadIdx.x;
  #pragma unroll
  for (int k = 0; k < 4; ++k) {
    int e = t + 256 * k;
    int c = e >> 4, n4 = e & 15;
    float4 v = *reinterpret_cast<const float4*>(&src[(size_t)(cb + c) * NPIX + nb + n4 * 4]);
    T[c][n4 * 4 + 0] = v.x; T[c][n4 * 4 + 1] = v.y;
    T[c][n4 * 4 + 2] = v.z; T[c][n4 * 4 + 3] = v.w;
  }
  __syncthreads();
  const int n = t >> 2, cq = t & 3, c0 = cq * 16;
  alignas(16) u16 hh[16], ll[16];
  #pragma unroll
  for (int j = 0; j < 16; ++j) fsplit(T[c0 + j][n], hh[j], ll[j]);
  size_t base = ((size_t)b * NPIX + nb + n) * CCH + cb + c0;
  *reinterpret_cast<uint4*>(&dh[base])     = *reinterpret_cast<uint4*>(hh);
  *reinterpret_cast<uint4*>(&dh[base + 8]) = *reinterpret_cast<uint4*>(hh + 8);
  *reinterpret_cast<uint4*>(&dl[base])     = *reinterpret_cast<uint4*>(ll);
  *reinterpret_cast<uint4*>(&dl[base + 8]) = *reinterpret_cast<uint4*>(ll + 8);
}

// ---------------------------------------------------------------------------
// u_gemv: u[row] = sum_c g[c]*(xh[row][c]+xl[row][c]).  grid NTOT/16, blk 256.
// ---------------------------------------------------------------------------
__global__ __launch_bounds__(256) void u_gemv(
    const u16* __restrict__ xh, const u16* __restrict__ xl,
    const float* __restrict__ g, float* __restrict__ u)
{
  __shared__ float sg[256];
  sg[threadIdx.x] = g[threadIdx.x];
  __syncthreads();
  const int wid = threadIdx.x >> 6, lane = threadIdx.x & 63;
  const int rl = lane >> 4, x = lane & 15;
  const int row = blockIdx.x * 16 + wid * 4 + rl;
  const int c0 = x * 16;
  const u16* ph = xh + (size_t)row * 256 + c0;
  const u16* pl = xl + (size_t)row * 256 + c0;
  f16x8 h0 = ld8(ph), h1 = ld8(ph + 8), l0 = ld8(pl), l1 = ld8(pl + 8);
  float s = 0.f;
  #pragma unroll
  for (int j = 0; j < 8; ++j) {
    s = fmaf((float)h0[j] + (float)l0[j], sg[c0 + j], s);
    s = fmaf((float)h1[j] + (float)l1[j], sg[c0 + 8 + j], s);
  }
  s += __shfl_xor(s, 1, 64);
  s += __shfl_xor(s, 2, 64);
  s += __shfl_xor(s, 4, 64);
  s += __shfl_xor(s, 8, 64);
  if (x == 0) u[row] = s;
}

// ---------------------------------------------------------------------------
// conv_s0: out[n][o] = A[n][c] * W[o][c]^T + bias.  A streamed via LDS,
// W resident (B-frags). Block 512 = 8 waves; tile 64n x 128o.
// PL = streamed planes. OM 0: split h/l out planes. OM 1: single + ReLU.
// ---------------------------------------------------------------------------
template<int PL, int OM>
__global__ __launch_bounds__(512) void conv_s0(
    const u16* __restrict__ Ah, const u16* __restrict__ Al,
    const u16* __restrict__ Wh, const u16* __restrict__ Wl,
    const float* __restrict__ bias, u16* __restrict__ Oh, u16* __restrict__ Ol)
{
  __shared__ alignas(16) u16 sA[PL * 64 * 256];
  const int nb = blockIdx.x * 64, ob = blockIdx.y * 128;
  const int tid = threadIdx.x, wid = tid >> 6, lane = tid & 63;
  const int gg = lane >> 4, x = lane & 15;
  const int wn = wid & 1, wo = wid >> 1;

  f16x8 bh[2][8], bl[2][8];
  #pragma unroll
  for (int os = 0; os < 2; ++os) {
    const int row = ob + wo * 32 + os * 16 + x;
    #pragma unroll
    for (int kc = 0; kc < 8; ++kc) {
      bh[os][kc] = ld8(&Wh[(size_t)row * 256 + kc * 32 + gg * 8]);
      bl[os][kc] = ld8(&Wl[(size_t)row * 256 + kc * 32 + gg * 8]);
    }
  }
  const u16* Ap[2] = {Ah, Al};
  #pragma unroll
  for (int p = 0; p < PL; ++p)
    #pragma unroll
    for (int r = 0; r < 4; ++r) {
      int e = tid + 512 * r;
      int row = e >> 5, ch = e & 31;
      gl2lds16(Ap[p] + (size_t)(nb + row) * 256 + ((ch ^ (row & 7)) * 8),
               &sA[p * 16384 + e * 8]);
    }
  __syncthreads();

  f32x4 acc[2][2] = {};
  #pragma unroll
  for (int ms = 0; ms < 2; ++ms) {
    const int row = wn * 32 + ms * 16 + x;
    #pragma unroll
    for (int kc = 0; kc < 8; ++kc) {
      const int off = row * 256 + (((kc * 4 + gg) ^ (x & 7)) * 8);
      f16x8 a0 = ld8(&sA[off]);
      #pragma unroll
      for (int os = 0; os < 2; ++os) {
        acc[ms][os] = mm(a0, bh[os][kc], acc[ms][os]);
        acc[ms][os] = mm(a0, bl[os][kc], acc[ms][os]);
      }
      if (PL == 2) {
        f16x8 a1 = ld8(&sA[16384 + off]);
        #pragma unroll
        for (int os = 0; os < 2; ++os)
          acc[ms][os] = mm(a1, bh[os][kc], acc[ms][os]);
      }
    }
  }
  #pragma unroll
  for (int os = 0; os < 2; ++os) {
    const float bo = bias ? bias[ob + wo * 32 + os * 16 + x] : 0.f;
    const size_t col = ob + wo * 32 + os * 16 + x;
    #pragma unroll
    for (int ms = 0; ms < 2; ++ms)
      #pragma unroll
      for (int j = 0; j < 4; ++j) {
        float val = acc[ms][os][j] + bo;
        size_t row = nb + wn * 32 + ms * 16 + gg * 4 + j;
        if (OM == 1) {
          Oh[row * 256 + col] = f2h(fmaxf(val, 0.f));
        } else {
          u16 h, l; fsplit(val, h, l);
          Oh[row * 256 + col] = h;
          Ol[row * 256 + col] = l;
        }
      }
  }
}

// ---------------------------------------------------------------------------
// conv_s1: out[o][n] = W[o][c] * B[n][c]^T + bias.  W resident (A-frags),
// B streamed via LDS. Block 512; tile 128o x 64n.
// PL = streamed planes. OM 0: single u16 plane out; OM 1: f32 out.
// ---------------------------------------------------------------------------
template<int PL, int OM>
__global__ __launch_bounds__(512) void conv_s1(
    const u16* __restrict__ Wh, const u16* __restrict__ Wl,
    const u16* __restrict__ Bh, const u16* __restrict__ Bl,
    const float* __restrict__ bias, void* __restrict__ Out)
{
  __shared__ alignas(16) u16 sB[PL * 64 * 256];
  const int nb = blockIdx.x * 64, ob = blockIdx.y * 128;
  const int tid = threadIdx.x, wid = tid >> 6, lane = tid & 63;
  const int gg = lane >> 4, x = lane & 15;
  const int wn = wid & 1, wo = wid >> 1;

  f16x8 ah[2][8], al[2][8];
  #pragma unroll
  for (int as = 0; as < 2; ++as) {
    const int row = ob + wo * 32 + as * 16 + x;
    #pragma unroll
    for (int kc = 0; kc < 8; ++kc) {
      ah[as][kc] = ld8(&Wh[(size_t)row * 256 + kc * 32 + gg * 8]);
      al[as][kc] = ld8(&Wl[(size_t)row * 256 + kc * 32 + gg * 8]);
    }
  }
  const u16* Bp[2] = {Bh, Bl};
  #pragma unroll
  for (int p = 0; p < PL; ++p)
    #pragma unroll
    for (int r = 0; r < 4; ++r) {
      int e = tid + 512 * r;
      int row = e >> 5, ch = e & 31;
      gl2lds16(Bp[p] + (size_t)(nb + row) * 256 + ((ch ^ (row & 7)) * 8),
               &sB[p * 16384 + e * 8]);
    }
  __syncthreads();

  f32x4 acc[2][2] = {};
  #pragma unroll
  for (int ns = 0; ns < 2; ++ns) {
    const int row = wn * 32 + ns * 16 + x;
    #pragma unroll
    for (int kc = 0; kc < 8; ++kc) {
      const int off = row * 256 + (((kc * 4 + gg) ^ (x & 7)) * 8);
      f16x8 b0 = ld8(&sB[off]);
      #pragma unroll
      for (int as = 0; as < 2; ++as) {
        acc[as][ns] = mm(ah[as][kc], b0, acc[as][ns]);
        acc[as][ns] = mm(al[as][kc], b0, acc[as][ns]);
      }
      if (PL == 2) {
        f16x8 b1 = ld8(&sB[16384 + off]);
        #pragma unroll
        for (int as = 0; as < 2; ++as)
          acc[as][ns] = mm(ah[as][kc], b1, acc[as][ns]);
      }
    }
  }
  #pragma unroll
  for (int as = 0; as < 2; ++as)
    #pragma unroll
    for (int j = 0; j < 4; ++j) {
      const int o = ob + wo * 32 + as * 16 + gg * 4 + j;
      const float bo = bias[o];
      #pragma unroll
      for (int ns = 0; ns < 2; ++ns) {
        int nf = nb + wn * 32 + ns * 16 + x;
        float val = acc[as][ns][j] + bo;
        int b_ = nf >> 12, n_ = nf & 4095;
        size_t addr = ((size_t)b_ * 256 + o) * 4096 + n_;
        if (OM == 1) ((float*)Out)[addr] = val;
        else         ((u16*)Out)[addr] = f2h(val);
      }
    }
}

// ---------------------------------------------------------------------------
// MFMA flash attention. S = Xq^T * Y + u[key]  (Y = M*Xkv precomputed).
// 3-term fp16 QK^T, 1-term PV. 8 waves = 4 q-groups x 2 key-halves.
// Counted-vmcnt pipeline: raw s_barrier + asm waits; ledger per iter:
//   entry: {V(t):4} -> QK -> lgkm0+bar -> +K(t+1):8 -> softmax
//   -> vmcnt(8)+bar (V ready) -> PV -> lgkm0+bar -> +V(t+1):4
//   -> vmcnt(4)+bar (K ready).  Wrap-staging at t=63 keeps ledger uniform.
// ---------------------------------------------------------------------------
__global__ __launch_bounds__(512) void attn_mfma(
    const u16* __restrict__ Qh, const u16* __restrict__ Ql,   // XqT planes
    const u16* __restrict__ Kh, const u16* __restrict__ Kl,   // Y planes [m][c]
    const u16* __restrict__ Vs,                               // V [c][n]
    const float* __restrict__ uB,                             // u [b][m]
    u16* __restrict__ AVt)
{
  __shared__ alignas(16) u16 smem[49152];   // 96 KB: sKh|sKl|sV, reused as Obuf
  __shared__ alignas(16) float sU[4096];    // 16 KB: u row for this batch
  __shared__ float sMm[2][64], sMl[2][64];
  u16* sKh = smem;
  u16* sKl = smem + 16384;
  u16* sV  = smem + 32768;

  const int b = blockIdx.y, qb = blockIdx.x * 64;
  const int tid = threadIdx.x, wid = tid >> 6;
  const int g = wid & 3, par = wid >> 2;
  const int lane = tid & 63, gg = lane >> 4, x = lane & 15;

  f16x8 qh[8], ql[8];
  {
    const u16* qhp = Qh + ((size_t)b * NPIX + qb + g * 16 + x) * CCH;
    const u16* qlp = Ql + ((size_t)b * NPIX + qb + g * 16 + x) * CCH;
    #pragma unroll
    for (int kc = 0; kc < 8; ++kc) {
      qh[kc] = ld8(qhp + kc * 32 + gg * 8);
      ql[kc] = ld8(qlp + kc * 32 + gg * 8);
    }
  }
  int kSrc[4], kDst[4], vSrc[4], vDst[4];
  #pragma unroll
  for (int r = 0; r < 4; ++r) {
    int e = tid + 512 * r;
    int m = e >> 5, ch = e & 31;
    kSrc[r] = m * CCH + ((ch ^ (m & 7)) * 8);
    kDst[r] = e * 8;
    int c = e >> 3, c2 = e & 7;
    vSrc[r] = c * NPIX + ((c2 ^ (c & 7)) * 8);
    vDst[r] = e * 8;
  }
  const u16* KhB = Kh + (size_t)b * NPIX * CCH;
  const u16* KlB = Kl + (size_t)b * NPIX * CCH;
  const u16* VB  = Vs + (size_t)b * CCH * NPIX;
  const char* uBb = (const char*)(uB + (size_t)b * NPIX);

#define STAGE_K(KO) do {                                        \
    _Pragma("unroll")                                           \
    for (int r_ = 0; r_ < 4; ++r_) {                            \
      size_t src_ = (KO) + kSrc[r_];                            \
      gl2lds16(KhB + src_, &sKh[kDst[r_]]);                     \
      gl2lds16(KlB + src_, &sKl[kDst[r_]]);                     \
    } } while (0)

#define STAGE_V(VO) do {                                        \
    _Pragma("unroll")                                           \
    for (int r_ = 0; r_ < 4; ++r_)                              \
      gl2lds16(VB + (VO) + vSrc[r_], &sV[vDst[r_]]);            \
    } while (0)

  f32x4 Oacc[16];
  #pragma unroll
  for (int i = 0; i < 16; ++i) Oacc[i] = f32x4{0.f, 0.f, 0.f, 0.f};
  float m_run = -INFINITY, l_run = 0.f;

  // prologue: K(0), V(0), u row; drain; barrier.
  STAGE_K((size_t)0);
  STAGE_V((size_t)0);
  #pragma unroll
  for (int j = 0; j < 2; ++j) {
    int e = tid + 512 * j;
    gl2lds16(uBb + e * 16, &sU[e * 4]);
  }
  ASMW("vmcnt(0)"); SB(); BARN(); SB();

  for (int mt = 0; mt < 64; ++mt) {
    // ---- QK^T over K(t), + u[key] ----
    f32x4 St[2];
    St[0] = f32x4{0.f, 0.f, 0.f, 0.f};
    St[1] = f32x4{0.f, 0.f, 0.f, 0.f};
    #pragma unroll
    for (int msub = 0; msub < 2; ++msub) {
      const int rb = (par * 32 + msub * 16 + x) * CCH;
      #pragma unroll
      for (int kc = 0; kc < 8; ++kc) {
        const int off = rb + (((kc * 4 + gg) ^ (x & 7)) * 8);
        f16x8 ah_ = ld8(&sKh[off]);
        f16x8 al_ = ld8(&sKl[off]);
        St[msub] = mm(ah_, qh[kc], St[msub]);
        St[msub] = mm(ah_, ql[kc], St[msub]);
        St[msub] = mm(al_, qh[kc], St[msub]);
      }
    }
    {
      f32x4 u0 = *reinterpret_cast<const f32x4*>(&sU[mt * 64 + par * 32 + gg * 4]);
      f32x4 u1 = *reinterpret_cast<const f32x4*>(&sU[mt * 64 + par * 32 + 16 + gg * 4]);
      St[0] += u0;
      St[1] += u1;
    }
    ASMW("lgkmcnt(0)"); SB(); BARN(); SB();      // K buffer free

    STAGE_K((size_t)((mt + 1) & 63) * (64 * CCH));   // 8 ops in flight

    // ---- online softmax with defer-max (THR=8) ----
    float vmax = fmaxf(fmaxf(fmaxf(St[0][0], St[0][1]), fmaxf(St[0][2], St[0][3])),
                       fmaxf(fmaxf(St[1][0], St[1][1]), fmaxf(St[1][2], St[1][3])));
    vmax = fmaxf(vmax, __shfl_xor(vmax, 16, 64));
    vmax = fmaxf(vmax, __shfl_xor(vmax, 32, 64));
    float alpha = 1.f;
    if (!__all(vmax <= m_run + 8.f)) {
      const float mnew = fmaxf(m_run, vmax);
      alpha = __expf(m_run - mnew);
      m_run = mnew;
      #pragma unroll
      for (int i = 0; i < 16; ++i) Oacc[i] *= alpha;
    }
    float p[2][4], ps = 0.f;
    #pragma unroll
    for (int msx = 0; msx < 2; ++msx)
      #pragma unroll
      for (int r = 0; r < 4; ++r) {
        p[msx][r] = __expf(St[msx][r] - m_run);
        ps += p[msx][r];
      }
    ps += __shfl_xor(ps, 16, 64);
    ps += __shfl_xor(ps, 32, 64);
    l_run = l_run * alpha + ps;

    // ---- pack P fp16, route to PV B-frag via 8 shfls ----
    u32 Pp[2][2];
    #pragma unroll
    for (int msx = 0; msx < 2; ++msx) {
      Pp[msx][0] = pkh(p[msx][0], p[msx][1]);
      Pp[msx][1] = pkh(p[msx][2], p[msx][3]);
    }
    const int src0 = ((gg & 1) * 2) * 16 + x, src1 = src0 + 16;
    const bool sel = (gg >> 1) != 0;
    union { u32 u[4]; f16x8 v; } pb;
    {
      u32 a0 = shflu(Pp[0][0], src0), a1 = shflu(Pp[1][0], src0);
      u32 b0 = shflu(Pp[0][1], src0), b1 = shflu(Pp[1][1], src0);
      u32 c0 = shflu(Pp[0][0], src1), c1 = shflu(Pp[1][0], src1);
      u32 d0 = shflu(Pp[0][1], src1), d1 = shflu(Pp[1][1], src1);
      pb.u[0] = sel ? a1 : a0;
      pb.u[1] = sel ? b1 : b0;
      pb.u[2] = sel ? c1 : c0;
      pb.u[3] = sel ? d1 : d0;
    }

    ASMW("vmcnt(8)"); SB(); BARN(); SB();        // V(t) landed everywhere

    // ---- PV: single MFMA per channel-slice ----
    #pragma unroll
    for (int cs = 0; cs < 16; ++cs) {
      const int off = (cs * 16 + x) * 64 + (((par * 4 + gg) ^ (x & 7)) * 8);
      Oacc[cs] = mm(ld8(&sV[off]), pb.v, Oacc[cs]);
    }
    ASMW("lgkmcnt(0)"); SB(); BARN(); SB();      // V buffer free

    STAGE_V((size_t)((mt + 1) & 63) * 64);       // 4 ops in flight

    ASMW("vmcnt(4)"); SB(); BARN(); SB();        // K(t+1) landed everywhere
  }

  ASMW("vmcnt(0) lgkmcnt(0)"); SB(); BARN(); SB();   // drain wrap-stages

  // ---- merge key-halves, normalize, transpose, store AVt [n][c] fp16 ----
  const int q = g * 16 + x;
  if (gg == 0) { sMm[par][q] = m_run; sMl[par][q] = l_run; }
  ASMW("lgkmcnt(0)"); SB(); BARN(); SB();
  const float mo = sMm[1 - par][q], lo = sMl[1 - par][q];
  const float mtot = fmaxf(m_run, mo);
  const float w = __expf(m_run - mtot), wo_ = __expf(mo - mtot);
  const float lt = l_run * w + lo * wo_;
  const float sc = w / lt;
  #pragma unroll
  for (int i = 0; i < 16; ++i) Oacc[i] *= sc;

  float* Obuf = reinterpret_cast<float*>(smem);
  #define OFF_(G, C, X) ((G) * 4360 + (C) * 17 + (X))
  if (par == 1) {
    #pragma unroll
    for (int cs = 0; cs < 16; ++cs)
      #pragma unroll
      for (int r = 0; r < 4; ++r)
        Obuf[OFF_(g, cs * 16 + gg * 4 + r, x)] = Oacc[cs][r];
  }
  ASMW("lgkmcnt(0)"); SB(); BARN(); SB();
  if (par == 0) {
    #pragma unroll
    for (int cs = 0; cs < 16; ++cs)
      #pragma unroll
      for (int r = 0; r < 4; ++r)
        Obuf[OFF_(g, cs * 16 + gg * 4 + r, x)] += Oacc[cs][r];
  }
  ASMW("lgkmcnt(0)"); SB(); BARN(); SB();
  const int n_loc = tid & 63, cq = tid >> 6;
  const int g2 = n_loc >> 4, x2 = n_loc & 15, c0 = cq * 32;
  alignas(16) u32 wds[16];
  #pragma unroll
  for (int j = 0; j < 16; ++j)
    wds[j] = pkh(Obuf[OFF_(g2, c0 + 2 * j, x2)], Obuf[OFF_(g2, c0 + 2 * j + 1, x2)]);
  u16* dst = AVt + ((size_t)b * NPIX + qb + n_loc) * CCH + c0;
  #pragma unroll
  for (int k = 0; k < 4; ++k)
    *reinterpret_cast<uint4*>(dst + k * 8) = *reinterpret_cast<uint4*>(&wds[k * 4]);
}

// ---------------------------------------------------------------------------
extern "C" void kernel_launch(void* const* d_in, const int* in_sizes, int n_in,
                              void* d_out, int out_size, void* d_ws, size_t ws_size,
                              hipStream_t stream) {
  const float* x_q  = (const float*)d_in[0];
  const float* x_kv = (const float*)d_in[1];
  const float* Wq = (const float*)d_in[2];
  const float* bq = (const float*)d_in[3];
  const float* Wk = (const float*)d_in[4];
  const float* bk = (const float*)d_in[5];   // cancels in softmax (row-term)
  const float* Wv = (const float*)d_in[6];
  const float* bv = (const float*)d_in[7];
  const float* W1 = (const float*)d_in[8];
  const float* b1 = (const float*)d_in[9];
  const float* W2 = (const float*)d_in[10];
  const float* b2 = (const float*)d_in[11];
  float* out = (float*)d_out;
  (void)bk;

  u16* ws = (u16*)d_ws;
  const size_t P = (size_t)NTOT * CCH;   // 4,194,304 elements per plane
  u16* xqTh  = ws;
  u16* xqTl  = ws + P;
  u16* xkvTh = ws + 2 * P;
  u16* xkvTl = ws + 3 * P;
  u16* Wp    = ws + 4 * P;               // 8 planes x 65536 (M,Wv,W1,W2)
  u16* Mh  = Wp + 0 * 65536, *Ml  = Wp + 1 * 65536;
  u16* Wvh = Wp + 2 * 65536, *Wvl = Wp + 3 * 65536;
  u16* W1h = Wp + 4 * 65536, *W1l = Wp + 5 * 65536;
  u16* W2h = Wp + 6 * 65536, *W2l = Wp + 7 * 65536;
  float* Mf32 = (float*)(Wp + 8 * 65536);        // 65536 f32
  float* gv   = (float*)(Wp + 8 * 65536 + 131072);   // 256 f32
  float* uB   = (float*)(Wp + 8 * 65536 + 131584);   // 16384 f32
  u16* Yh  = ws + 5 * P;
  u16* Yl  = ws + 6 * P;
  u16* Vhp = ws + 7 * P;
  u16* AVt = ws + 8 * P;
  u16* HIDt = xqTh;   // xqT dead after attn

  mm_wqwk<<<dim3(4, 4), 256, 0, stream>>>(Wq, Wk, Mf32);
  gvec<<<1, 256, 0, stream>>>(Wk, bq, gv);
  transpose_split<<<dim3(64, 4, 8), 256, 0, stream>>>(
      x_q, x_kv, xqTh, xqTl, xkvTh, xkvTl);
  prep_w<<<dim3(64, 4), 256, 0, stream>>>(Mf32, Wv, W1, W2, Wp);

  conv_s0<2, 0><<<dim3(256, 2), 512, 0, stream>>>(
      xkvTh, xkvTl, Mh, Ml, nullptr, Yh, Yl);                  // Y = M*Xkv
  conv_s1<2, 0><<<dim3(256, 2), 512, 0, stream>>>(
      Wvh, Wvl, xkvTh, xkvTl, bv, (void*)Vhp);                 // V
  u_gemv<<<dim3(NTOT / 16), 256, 0, stream>>>(xkvTh, xkvTl, gv, uB);

  attn_mfma<<<dim3(NPIX / 64, NB), 512, 0, stream>>>(
      xqTh, xqTl, Yh, Yl, Vhp, uB, AVt);

  conv_s0<1, 1><<<dim3(256, 2), 512, 0, stream>>>(
      AVt, nullptr, W1h, W1l, b1, HIDt, nullptr);
  conv_s1<1, 1><<<dim3(256, 2), 512, 0, stream>>>(
      W2h, W2l, HIDt, nullptr, b2, (void*)out);
}